// Round 13
// baseline (53.796 us; speedup 1.0000x reference)
//
#include <hip/hip_runtime.h>
#include <hip/hip_bf16.h>
#include <hip/hip_fp16.h>
#include <cfloat>

// Problem constants
#define BB   16
#define LL   4096
#define CC   9
#define DIN  512
#define DOUT 128
#define VV   96
#define ROWS (BB * LL)

// LDS / layout constants
#define BLD2 136    // phase-A B tile row stride (128 + 8) halves
#define SLD2 100    // phase-A S tile row stride f32
#define PELD 136    // PE row stride halves
#define SPAD 12     // Sp padded row (9 -> 12 floats)

typedef _Float16 f16x8 __attribute__((ext_vector_type(8)));
typedef _Float16 h2 __attribute__((ext_vector_type(2)));
typedef float f32x4 __attribute__((ext_vector_type(4)));

__device__ __forceinline__ unsigned int pk2(float lo, float hi) {
    return __builtin_bit_cast(unsigned int, __builtin_amdgcn_cvt_pkrtz(lo, hi));
}

// ---------------------------------------------------------------------------
// Kernel 1: PW[v][k] = sum_o PE[v][o]*W[o][k] -> fp16; y==0 also converts PEh.
// ---------------------------------------------------------------------------
__global__ __launch_bounds__(128)
void pw_kernel(const float* __restrict__ W,    // [DOUT][DIN]
               const float* __restrict__ PE,   // [VV][DOUT]
               __half*      __restrict__ PW,   // [VV][DIN]
               __half*      __restrict__ PEh)  // [VV][DOUT]
{
    const int v = blockIdx.x;                       // 0..95
    const int k = blockIdx.y * 128 + threadIdx.x;   // 0..511
    const float* per = PE + v * DOUT;
    float a = 0.f;
    #pragma unroll 8
    for (int o = 0; o < DOUT; ++o)
        a = fmaf(per[o], W[(size_t)o * DIN + k], a);
    PW[(size_t)v * DIN + k] = __float2half_rn(a);
    if (blockIdx.y == 0)
        PEh[(size_t)v * DOUT + threadIdx.x] = __float2half_rn(per[threadIdx.x]);
}

// ---------------------------------------------------------------------------
// Kernel 2 (phase A): S_kq[row][c] = sum_{k in quarter} X[row][k]*PW[ci][k]
// via dense MFMA of all 96 columns, then gather 9.
// grid (ROWS/64, 4), 256 threads = 4 waves; LDS 26 KB -> ~6 blocks/CU.
// ---------------------------------------------------------------------------
__global__ __launch_bounds__(256)
void score_kernel(const float*  __restrict__ X,     // [ROWS][DIN]
                  const __half* __restrict__ PW,    // [VV][DIN]
                  const int*    __restrict__ CIDX,  // [ROWS][CC]
                  float*        __restrict__ Sp)    // [4][ROWS][SPAD]
{
    __shared__ __align__(16) unsigned char raw[VV * BLD2 * 2];  // 26112 B
    __half* Bl = (__half*)raw;        // [VV][BLD2] halves
    float*  St = (float*)raw;         // [64][SLD2] f32 (reused after MFMA)

    const int t    = threadIdx.x;
    const int kq   = blockIdx.y;      // 0..3
    const int K0   = kq * 128;
    const int lane = t & 63;
    const int wid  = t >> 6;          // 0..3
    const int fr   = lane & 15;
    const int hi   = lane >> 4;       // 0..3
    const int row0 = blockIdx.x * 64;
    const int arow = row0 + wid * 16 + fr;

    // ---- all A loads upfront (8 float4 = this row's k-quarter) ----
    const float* xr = X + (size_t)arow * DIN + K0 + hi * 8;
    float4 A[8];
    #pragma unroll
    for (int ks = 0; ks < 4; ++ks) {
        A[2 * ks]     = *(const float4*)(xr + ks * 32);
        A[2 * ks + 1] = *(const float4*)(xr + ks * 32 + 4);
    }

    // ---- stage B: PW[0..95][K0..K0+128) -> LDS (1536 uint4, 6/thread) ----
    #pragma unroll
    for (int i = 0; i < 6; ++i) {
        int chunk = t + i * 256;
        int v = chunk >> 4, kk = (chunk & 15) * 8;
        *(uint4*)&Bl[v * BLD2 + kk] = *(const uint4*)(PW + (size_t)v * DIN + K0 + kk);
    }
    __syncthreads();

    // ---- 4 k-steps x 6 col-frags MFMA ----
    f32x4 acc[6];
    #pragma unroll
    for (int nf = 0; nf < 6; ++nf) acc[nf] = (f32x4)0.f;

    #pragma unroll
    for (int ks = 0; ks < 4; ++ks) {
        uint4 up;
        up.x = pk2(A[2 * ks].x,     A[2 * ks].y);
        up.y = pk2(A[2 * ks].z,     A[2 * ks].w);
        up.z = pk2(A[2 * ks + 1].x, A[2 * ks + 1].y);
        up.w = pk2(A[2 * ks + 1].z, A[2 * ks + 1].w);
        f16x8 af = __builtin_bit_cast(f16x8, up);
        #pragma unroll
        for (int nf = 0; nf < 6; ++nf) {
            f16x8 bf = *(const f16x8*)&Bl[(nf * 16 + fr) * BLD2 + ks * 32 + hi * 8];
            acc[nf] = __builtin_amdgcn_mfma_f32_16x16x32_f16(af, bf, acc[nf], 0, 0, 0);
        }
    }
    __syncthreads();   // B reads done; reuse LDS as S tile

    // ---- write S tile (D layout: col=lane&15, row=(lane>>4)*4+j; r10-verified) ----
    #pragma unroll
    for (int nf = 0; nf < 6; ++nf) {
        #pragma unroll
        for (int jj = 0; jj < 4; ++jj)
            St[(wid * 16 + hi * 4 + jj) * SLD2 + nf * 16 + fr] = acc[nf][jj];
    }
    __syncthreads();

    // ---- gather 9 candidate scores -> Sp ----
    const int r_e = t >> 2, sub = t & 3;
    const int grow = row0 + r_e;
    float* spr = Sp + ((size_t)kq * ROWS + grow) * SPAD;
    #pragma unroll
    for (int c = sub; c < CC; c += 4) {
        int v = CIDX[(size_t)grow * CC + c];
        spr[c] = St[r_e * SLD2 + v];
    }
}

// ---------------------------------------------------------------------------
// Kernel 3 (phase B): sum partials -> masked softmax -> PV from PEh LDS.
// grid ROWS/64, 256 threads, 4 lanes/row.
// ---------------------------------------------------------------------------
__global__ __launch_bounds__(256)
void finish_kernel(const float*  __restrict__ Sp,    // [4][ROWS][SPAD]
                   const __half* __restrict__ PEh,   // [VV][DOUT]
                   const int*    __restrict__ CIDX,  // [ROWS][CC]
                   const int*    __restrict__ CMASK, // [ROWS][CC]
                   const int*    __restrict__ SLEN,  // [BB]
                   float*        __restrict__ OUT)   // [ROWS][DOUT]
{
    __shared__ __half pe[VV * PELD];   // 26112 B

    const int t = threadIdx.x;
    #pragma unroll
    for (int i = 0; i < 6; ++i) {
        int chunk = t + i * 256;
        int v = chunk >> 4, kk = (chunk & 15) * 8;
        *(uint4*)&pe[v * PELD + kk] = *(const uint4*)(PEh + (size_t)v * DOUT + kk);
    }

    const int r_e = t >> 2, sub = t & 3;
    const int row = blockIdx.x * 64 + r_e;
    const int b   = row >> 12, l = row & (LL - 1);
    const bool inlen = l < SLEN[b];

    int ci[CC], vm[CC];
    #pragma unroll
    for (int c = 0; c < CC; ++c) ci[c] = CIDX[(size_t)row * CC + c];
    #pragma unroll
    for (int c = 0; c < CC; ++c) vm[c] = CMASK[(size_t)row * CC + c];

    float sc[CC];
    #pragma unroll
    for (int c = 0; c < CC; ++c) sc[c] = 0.f;
    #pragma unroll
    for (int kq = 0; kq < 4; ++kq) {
        const float* sp = Sp + ((size_t)kq * ROWS + row) * SPAD;
        float4 s0 = *(const float4*)sp;
        float4 s1 = *(const float4*)(sp + 4);
        float  s2 = sp[8];
        sc[0] += s0.x; sc[1] += s0.y; sc[2] += s0.z; sc[3] += s0.w;
        sc[4] += s1.x; sc[5] += s1.y; sc[6] += s1.z; sc[7] += s1.w;
        sc[8] += s2;
    }

    bool any = false;
    float mx = -FLT_MAX;
    #pragma unroll
    for (int c = 0; c < CC; ++c)
        if (vm[c]) { mx = fmaxf(mx, sc[c]); any = true; }
    float e[CC], den = 0.f;
    #pragma unroll
    for (int c = 0; c < CC; ++c) {
        e[c] = vm[c] ? __expf(sc[c] - mx) : 0.f;
        den += e[c];
    }
    const float scale = (any && inlen) ? (1.f / den) : 0.f;

    __syncthreads();   // PE staged

    float o[32];
    #pragma unroll
    for (int j = 0; j < 32; ++j) o[j] = 0.f;
    #pragma unroll
    for (int c = 0; c < CC; ++c) {
        const float w = e[c];
        const __half* per = pe + ci[c] * PELD + sub * 32;
        #pragma unroll
        for (int q = 0; q < 4; ++q) {
            uint4 u = *(const uint4*)(per + q * 8);
            h2 h0 = __builtin_bit_cast(h2, u.x);
            h2 h1 = __builtin_bit_cast(h2, u.y);
            h2 h2v_ = __builtin_bit_cast(h2, u.z);
            h2 h3 = __builtin_bit_cast(h2, u.w);
            o[q * 8 + 0] = fmaf(w, (float)h0[0], o[q * 8 + 0]);
            o[q * 8 + 1] = fmaf(w, (float)h0[1], o[q * 8 + 1]);
            o[q * 8 + 2] = fmaf(w, (float)h1[0], o[q * 8 + 2]);
            o[q * 8 + 3] = fmaf(w, (float)h1[1], o[q * 8 + 3]);
            o[q * 8 + 4] = fmaf(w, (float)h2v_[0], o[q * 8 + 4]);
            o[q * 8 + 5] = fmaf(w, (float)h2v_[1], o[q * 8 + 5]);
            o[q * 8 + 6] = fmaf(w, (float)h3[0], o[q * 8 + 6]);
            o[q * 8 + 7] = fmaf(w, (float)h3[1], o[q * 8 + 7]);
        }
    }

    float* op = OUT + (size_t)row * DOUT + sub * 32;
    #pragma unroll
    for (int q = 0; q < 8; ++q) {
        float4 v = make_float4(o[q * 4 + 0] * scale, o[q * 4 + 1] * scale,
                               o[q * 4 + 2] * scale, o[q * 4 + 3] * scale);
        *(float4*)(op + q * 4) = v;
    }
}

extern "C" void kernel_launch(void* const* d_in, const int* in_sizes, int n_in,
                              void* d_out, int out_size, void* d_ws, size_t ws_size,
                              hipStream_t stream) {
    const float* X  = (const float*)d_in[0];
    const float* W  = (const float*)d_in[1];
    const float* PE = (const float*)d_in[2];
    const int*   CI = (const int*)d_in[3];
    const int*   CM = (const int*)d_in[4];
    const int*   SL = (const int*)d_in[5];
    float* OUT = (float*)d_out;

    unsigned char* ws = (unsigned char*)d_ws;
    __half* PW  = (__half*)ws;                         // 96*512*2  = 98304 B
    __half* PEh = (__half*)(ws + 98304);               // 96*128*2  = 24576 B
    float*  Sp  = (float*)(ws + 131072);               // 4*65536*12*4 = 12.6 MB

    hipLaunchKernelGGL(pw_kernel, dim3(VV, 4), dim3(128), 0, stream, W, PE, PW, PEh);
    hipLaunchKernelGGL(score_kernel, dim3(ROWS / 64, 4), dim3(256), 0, stream,
                       X, PW, CI, Sp);
    hipLaunchKernelGGL(finish_kernel, dim3(ROWS / 64), dim3(256), 0, stream,
                       Sp, PEh, CI, CM, SL, OUT);
}

// Round 16
// 52.424 us; speedup vs baseline: 1.0262x; 1.0262x over previous
//
#include <hip/hip_runtime.h>
#include <hip/hip_bf16.h>
#include <hip/hip_fp16.h>
#include <cfloat>

// Problem constants
#define BB   16
#define LL   4096
#define CC   9
#define DIN  512
#define DOUT 128
#define VV   96
#define ROWS (BB * LL)

// LDS geometry
#define BLD2 136    // B quarter-tile row stride (128 + 8) halves
#define SLD2 100    // S tile row stride f32 (aliased over B region)

typedef _Float16 f16x8 __attribute__((ext_vector_type(8)));
typedef _Float16 h2 __attribute__((ext_vector_type(2)));
typedef float f32x4 __attribute__((ext_vector_type(4)));

__device__ __forceinline__ unsigned int pk2(float lo, float hi) {
    return __builtin_bit_cast(unsigned int, __builtin_amdgcn_cvt_pkrtz(lo, hi));
}

// ---------------------------------------------------------------------------
// Kernel 1: PW[v][k] = sum_o PE[v][o]*W[o][k] -> fp16; y==0 also converts PEh.
// ---------------------------------------------------------------------------
__global__ __launch_bounds__(128)
void pw_kernel(const float* __restrict__ W,    // [DOUT][DIN]
               const float* __restrict__ PE,   // [VV][DOUT]
               __half*      __restrict__ PW,   // [VV][DIN]
               __half*      __restrict__ PEh)  // [VV][DOUT]
{
    const int v = blockIdx.x;                       // 0..95
    const int k = blockIdx.y * 128 + threadIdx.x;   // 0..511
    const float* per = PE + v * DOUT;
    float a = 0.f;
    #pragma unroll 8
    for (int o = 0; o < DOUT; ++o)
        a = fmaf(per[o], W[(size_t)o * DIN + k], a);
    PW[(size_t)v * DIN + k] = __float2half_rn(a);
    if (blockIdx.y == 0)
        PEh[(size_t)v * DOUT + threadIdx.x] = __float2half_rn(per[threadIdx.x]);
}

// ---------------------------------------------------------------------------
// Kernel 2: fused. Per block: 64 rows. Loop kq=0..3 { stage PW quarter in
// 26 KB LDS; S += X_q · PW_q^T via MFMA }. Then alias LDS as S tile, gather
// 9 scores/row, softmax, PV from global PEh (L1/L2-resident), store.
// 256 thr = 4 waves, LDS 26 KB -> ~6 blocks/CU.
// ---------------------------------------------------------------------------
__global__ __launch_bounds__(256)
void attn_kernel(const float*  __restrict__ X,     // [ROWS][DIN]
                 const __half* __restrict__ PW,    // [VV][DIN]
                 const __half* __restrict__ PEh,   // [VV][DOUT]
                 const int*    __restrict__ CIDX,  // [ROWS][CC]
                 const int*    __restrict__ CMASK, // [ROWS][CC]
                 const int*    __restrict__ SLEN,  // [BB]
                 float*        __restrict__ OUT)   // [ROWS][DOUT]
{
    __shared__ __align__(16) unsigned char raw[VV * BLD2 * 2];  // 26112 B
    __half* Bl = (__half*)raw;        // [VV][BLD2] halves (per quarter)
    float*  St = (float*)raw;         // [64][SLD2] f32 (aliased after MFMA)

    const int t    = threadIdx.x;
    const int lane = t & 63;
    const int wid  = t >> 6;          // 0..3
    const int fr   = lane & 15;
    const int hi   = lane >> 4;       // 0..3
    const int row0 = blockIdx.x * 64;
    const int arow = row0 + wid * 16 + fr;
    const float* xbase = X + (size_t)arow * DIN + hi * 8;

    f32x4 acc[6];
    #pragma unroll
    for (int nf = 0; nf < 6; ++nf) acc[nf] = (f32x4)0.f;

    #pragma unroll
    for (int kq = 0; kq < 4; ++kq) {
        const int K0 = kq * 128;

        // ---- A loads for this quarter (8 float4/thread) ----
        float4 A[8];
        #pragma unroll
        for (int ks = 0; ks < 4; ++ks) {
            A[2 * ks]     = *(const float4*)(xbase + K0 + ks * 32);
            A[2 * ks + 1] = *(const float4*)(xbase + K0 + ks * 32 + 4);
        }

        // ---- stage B quarter: PW[0..95][K0..K0+128) (1536 uint4, 6/thr) ----
        if (kq) __syncthreads();          // prev-quarter B reads complete
        #pragma unroll
        for (int i = 0; i < 6; ++i) {
            int chunk = t + i * 256;
            int v = chunk >> 4, kk = (chunk & 15) * 8;
            *(uint4*)&Bl[v * BLD2 + kk] =
                *(const uint4*)(PW + (size_t)v * DIN + K0 + kk);
        }
        __syncthreads();

        // ---- 4 k-steps x 6 col-frags MFMA ----
        #pragma unroll
        for (int ks = 0; ks < 4; ++ks) {
            uint4 up;
            up.x = pk2(A[2 * ks].x,     A[2 * ks].y);
            up.y = pk2(A[2 * ks].z,     A[2 * ks].w);
            up.z = pk2(A[2 * ks + 1].x, A[2 * ks + 1].y);
            up.w = pk2(A[2 * ks + 1].z, A[2 * ks + 1].w);
            f16x8 af = __builtin_bit_cast(f16x8, up);
            #pragma unroll
            for (int nf = 0; nf < 6; ++nf) {
                f16x8 bf = *(const f16x8*)&Bl[(nf * 16 + fr) * BLD2 + ks * 32 + hi * 8];
                acc[nf] = __builtin_amdgcn_mfma_f32_16x16x32_f16(af, bf, acc[nf], 0, 0, 0);
            }
        }
    }
    __syncthreads();   // all B reads done: alias LDS as S tile

    // ---- write S tile (D layout: col=lane&15, row=(lane>>4)*4+j) ----
    #pragma unroll
    for (int nf = 0; nf < 6; ++nf) {
        #pragma unroll
        for (int jj = 0; jj < 4; ++jj)
            St[(wid * 16 + hi * 4 + jj) * SLD2 + nf * 16 + fr] = acc[nf][jj];
    }
    __syncthreads();

    // ---- epilogue: 4 lanes per row ----
    const int r_e = t >> 2, sub = t & 3;
    const int row = row0 + r_e;
    const int b   = row >> 12, l = row & (LL - 1);
    const bool inlen = l < SLEN[b];

    int ci[CC], vm[CC];
    #pragma unroll
    for (int c = 0; c < CC; ++c) ci[c] = CIDX[(size_t)row * CC + c];
    #pragma unroll
    for (int c = 0; c < CC; ++c) vm[c] = CMASK[(size_t)row * CC + c];

    float sc[CC];
    #pragma unroll
    for (int c = 0; c < CC; ++c) sc[c] = St[r_e * SLD2 + ci[c]];

    bool any = false;
    float mx = -FLT_MAX;
    #pragma unroll
    for (int c = 0; c < CC; ++c)
        if (vm[c]) { mx = fmaxf(mx, sc[c]); any = true; }
    float e[CC], den = 0.f;
    #pragma unroll
    for (int c = 0; c < CC; ++c) {
        e[c] = vm[c] ? __expf(sc[c] - mx) : 0.f;
        den += e[c];
    }
    const float scale = (any && inlen) ? (1.f / den) : 0.f;

    // ---- PV from global PEh (24 KB table, L1/L2-resident) ----
    float o[32];
    #pragma unroll
    for (int j = 0; j < 32; ++j) o[j] = 0.f;
    #pragma unroll
    for (int c = 0; c < CC; ++c) {
        const float w = e[c];
        const __half* per = PEh + (size_t)ci[c] * DOUT + sub * 32;
        #pragma unroll
        for (int q = 0; q < 4; ++q) {
            uint4 u = *(const uint4*)(per + q * 8);
            h2 h0 = __builtin_bit_cast(h2, u.x);
            h2 h1 = __builtin_bit_cast(h2, u.y);
            h2 h2v_ = __builtin_bit_cast(h2, u.z);
            h2 h3 = __builtin_bit_cast(h2, u.w);
            o[q * 8 + 0] = fmaf(w, (float)h0[0],   o[q * 8 + 0]);
            o[q * 8 + 1] = fmaf(w, (float)h0[1],   o[q * 8 + 1]);
            o[q * 8 + 2] = fmaf(w, (float)h1[0],   o[q * 8 + 2]);
            o[q * 8 + 3] = fmaf(w, (float)h1[1],   o[q * 8 + 3]);
            o[q * 8 + 4] = fmaf(w, (float)h2v_[0], o[q * 8 + 4]);
            o[q * 8 + 5] = fmaf(w, (float)h2v_[1], o[q * 8 + 5]);
            o[q * 8 + 6] = fmaf(w, (float)h3[0],   o[q * 8 + 6]);
            o[q * 8 + 7] = fmaf(w, (float)h3[1],   o[q * 8 + 7]);
        }
    }

    float* op = OUT + (size_t)row * DOUT + sub * 32;
    #pragma unroll
    for (int q = 0; q < 8; ++q) {
        float4 v = make_float4(o[q * 4 + 0] * scale, o[q * 4 + 1] * scale,
                               o[q * 4 + 2] * scale, o[q * 4 + 3] * scale);
        *(float4*)(op + q * 4) = v;
    }
}

extern "C" void kernel_launch(void* const* d_in, const int* in_sizes, int n_in,
                              void* d_out, int out_size, void* d_ws, size_t ws_size,
                              hipStream_t stream) {
    const float* X  = (const float*)d_in[0];
    const float* W  = (const float*)d_in[1];
    const float* PE = (const float*)d_in[2];
    const int*   CI = (const int*)d_in[3];
    const int*   CM = (const int*)d_in[4];
    const int*   SL = (const int*)d_in[5];
    float* OUT = (float*)d_out;

    unsigned char* ws = (unsigned char*)d_ws;
    __half* PW  = (__half*)ws;                         // 96*512*2 = 98304 B
    __half* PEh = (__half*)(ws + 98304);               // 96*128*2 = 24576 B

    hipLaunchKernelGGL(pw_kernel, dim3(VV, 4), dim3(128), 0, stream, W, PE, PW, PEh);
    hipLaunchKernelGGL(attn_kernel, dim3(ROWS / 64), dim3(256), 0, stream,
                       X, PW, PEh, CI, CM, SL, OUT);
}

// Round 19
// 40.715 us; speedup vs baseline: 1.3213x; 1.2876x over previous
//
#include <hip/hip_runtime.h>
#include <hip/hip_bf16.h>
#include <hip/hip_fp16.h>
#include <cfloat>

// Problem constants
#define BB   16
#define LL   4096
#define CC   9
#define DIN  512
#define DOUT 128
#define VV   96

// LDS layout (halves): padded row strides (round-8 verified)
#define PWLD 520    // 512 + 8
#define PELD 136    // 128 + 8

typedef _Float16 h2 __attribute__((ext_vector_type(2)));

#if defined(__has_builtin)
#if __has_builtin(__builtin_amdgcn_fdot2)
#define FDOT2(a, b, c) __builtin_amdgcn_fdot2((a), (b), (c), false)
#endif
#endif
#ifndef FDOT2
__device__ __forceinline__ float FDOT2(h2 a, h2 b, float c) {
    return c + (float)a[0] * (float)b[0] + (float)a[1] * (float)b[1];
}
#endif

__device__ __forceinline__ h2 pack_h2(float lo, float hi) {
    return __builtin_bit_cast(h2, __builtin_amdgcn_cvt_pkrtz(lo, hi));
}

// ---------------------------------------------------------------------------
// Kernel 1: PW[v][k] = sum_o PE[v][o]*W[o][k] -> fp16; y==0 also converts PEh.
// ---------------------------------------------------------------------------
__global__ __launch_bounds__(128)
void pw_kernel(const float* __restrict__ W,    // [DOUT][DIN]
               const float* __restrict__ PE,   // [VV][DOUT]
               __half*      __restrict__ PW,   // [VV][DIN]
               __half*      __restrict__ PEh)  // [VV][DOUT]
{
    const int v = blockIdx.x;                       // 0..95
    const int k = blockIdx.y * 128 + threadIdx.x;   // 0..511
    const float* per = PE + v * DOUT;
    float a = 0.f;
    #pragma unroll 8
    for (int o = 0; o < DOUT; ++o)
        a = fmaf(per[o], W[(size_t)o * DIN + k], a);
    PW[(size_t)v * DIN + k] = __float2half_rn(a);
    if (blockIdx.y == 0)
        PEh[(size_t)v * DOUT + threadIdx.x] = __float2half_rn(per[threadIdx.x]);
}

// ---------------------------------------------------------------------------
// Kernel 2: round-8 structure (best known): PW + PEh staged in LDS;
// 16 lanes/row; 1024 thr = 64 row-slots; 128 rows/block over 2 iterations.
// Dead rows (pad / no-candidate) skip the X stream and store zeros.
// ---------------------------------------------------------------------------
__global__ __launch_bounds__(1024)
void attn_kernel(const float*  __restrict__ X,     // [B*L][DIN]
                 const __half* __restrict__ PW,    // [VV][DIN]
                 const __half* __restrict__ PEh,   // [VV][DOUT]
                 const int*    __restrict__ CIDX,  // [B*L][CC]
                 const int*    __restrict__ CMASK, // [B*L][CC]
                 const int*    __restrict__ SLEN,  // [B]
                 float*        __restrict__ OUT)   // [B*L][DOUT]
{
    __shared__ __half lds_pw[VV * PWLD];   // 99840 B
    __shared__ __half lds_pe[VV * PELD];   // 26112 B

    const int t = threadIdx.x;

    // ---- stage PW: 96*512/8 = 6144 uint4 chunks, 6 per thread ----
    #pragma unroll
    for (int it = 0; it < 6; ++it) {
        int chunk = t + it * 1024;
        int v = chunk >> 6, kq = chunk & 63;
        uint4 d = *(const uint4*)(PW + (size_t)v * DIN + kq * 8);
        *(uint4*)&lds_pw[v * PWLD + kq * 8] = d;
    }
    // ---- stage PEh: 96*128/8 = 1536 chunks ----
    {
        if (t < 1536) {
            int v = t >> 4, kq = t & 15;
            *(uint4*)&lds_pe[v * PELD + kq * 8] =
                *(const uint4*)(PEh + (size_t)v * DOUT + kq * 8);
        }
        int c2 = t + 1024;
        if (c2 < 1536) {
            int v2 = c2 >> 4, k2 = c2 & 15;
            *(uint4*)&lds_pe[v2 * PELD + k2 * 8] =
                *(const uint4*)(PEh + (size_t)v2 * DOUT + k2 * 8);
        }
    }
    __syncthreads();

    const int lane = t & 63;
    const int il   = lane & 15;          // lane within row-group
    const int slot = t >> 4;             // 0..63 row-slot in block
    const int rowbase = blockIdx.x * 128;

    #pragma unroll
    for (int iter = 0; iter < 2; ++iter) {
        const int row = rowbase + iter * 64 + slot;
        const int  b     = row >> 12;
        const int  l     = row & (LL - 1);
        const bool inlen = l < SLEN[b];

        // ---- candidate indices + mask (cheap, L2/L3-hot) ----
        int ci[CC], vm[CC];
        #pragma unroll
        for (int c = 0; c < CC; ++c) ci[c]  = CIDX[(size_t)row * CC + c];
        #pragma unroll
        for (int c = 0; c < CC; ++c) vm[c] = CMASK[(size_t)row * CC + c];
        int anym = 0;
        #pragma unroll
        for (int c = 0; c < CC; ++c) anym |= vm[c];
        const bool alive = inlen && (anym != 0);

        float* op = OUT + (size_t)row * DOUT + il * 8;

        if (!alive) {
            // dead row: no X traffic, store zeros
            *(float4*)op       = make_float4(0.f, 0.f, 0.f, 0.f);
            *(float4*)(op + 4) = make_float4(0.f, 0.f, 0.f, 0.f);
        } else {
            // ---- X loads (the dominant HBM stream; only for live rows) ----
            const float* xr = X + (size_t)row * DIN;
            float4 xf[8];
            #pragma unroll
            for (int j = 0; j < 4; ++j) {
                xf[j * 2 + 0] = *(const float4*)(xr + il * 8 + 128 * j);
                xf[j * 2 + 1] = *(const float4*)(xr + il * 8 + 128 * j + 4);
            }
            h2 xh[16];
            #pragma unroll
            for (int q = 0; q < 8; ++q) {
                xh[q * 2 + 0] = pack_h2(xf[q].x, xf[q].y);
                xh[q * 2 + 1] = pack_h2(xf[q].z, xf[q].w);
            }

            // ---- scores from LDS PW ----
            float sc[CC];
            #pragma unroll
            for (int c = 0; c < CC; ++c) sc[c] = 0.f;
            #pragma unroll
            for (int j = 0; j < 4; ++j) {
                #pragma unroll
                for (int c = 0; c < CC; ++c) {
                    uint4 pwb = *(const uint4*)&lds_pw[ci[c] * PWLD + j * 128 + il * 8];
                    h2 p0 = __builtin_bit_cast(h2, pwb.x);
                    h2 p1 = __builtin_bit_cast(h2, pwb.y);
                    h2 p2 = __builtin_bit_cast(h2, pwb.z);
                    h2 p3 = __builtin_bit_cast(h2, pwb.w);
                    float s = sc[c];
                    s = FDOT2(xh[j * 4 + 0], p0, s);
                    s = FDOT2(xh[j * 4 + 1], p1, s);
                    s = FDOT2(xh[j * 4 + 2], p2, s);
                    s = FDOT2(xh[j * 4 + 3], p3, s);
                    sc[c] = s;
                }
            }
            #pragma unroll
            for (int c = 0; c < CC; ++c) {
                float s = sc[c];
                s += __shfl_xor(s, 1);
                s += __shfl_xor(s, 2);
                s += __shfl_xor(s, 4);
                s += __shfl_xor(s, 8);
                sc[c] = s;
            }

            // ---- masked softmax (redundant per lane) ----
            float mx = -FLT_MAX;
            #pragma unroll
            for (int c = 0; c < CC; ++c)
                if (vm[c]) mx = fmaxf(mx, sc[c]);
            float e[CC], den = 0.f;
            #pragma unroll
            for (int c = 0; c < CC; ++c) {
                e[c] = vm[c] ? __expf(sc[c] - mx) : 0.f;
                den += e[c];
            }
            const float scale = 1.f / den;

            // ---- weighted PE sum from LDS ----
            float o[8];
            #pragma unroll
            for (int j = 0; j < 8; ++j) o[j] = 0.f;
            #pragma unroll
            for (int c = 0; c < CC; ++c) {
                const float w = e[c];
                uint4 peb = *(const uint4*)&lds_pe[ci[c] * PELD + il * 8];
                h2 q0 = __builtin_bit_cast(h2, peb.x);
                h2 q1 = __builtin_bit_cast(h2, peb.y);
                h2 q2 = __builtin_bit_cast(h2, peb.z);
                h2 q3 = __builtin_bit_cast(h2, peb.w);
                o[0] = fmaf(w, (float)q0[0], o[0]); o[1] = fmaf(w, (float)q0[1], o[1]);
                o[2] = fmaf(w, (float)q1[0], o[2]); o[3] = fmaf(w, (float)q1[1], o[3]);
                o[4] = fmaf(w, (float)q2[0], o[4]); o[5] = fmaf(w, (float)q2[1], o[5]);
                o[6] = fmaf(w, (float)q3[0], o[6]); o[7] = fmaf(w, (float)q3[1], o[7]);
            }

            *(float4*)op       = make_float4(o[0] * scale, o[1] * scale, o[2] * scale, o[3] * scale);
            *(float4*)(op + 4) = make_float4(o[4] * scale, o[5] * scale, o[6] * scale, o[7] * scale);
        }
    }
}

extern "C" void kernel_launch(void* const* d_in, const int* in_sizes, int n_in,
                              void* d_out, int out_size, void* d_ws, size_t ws_size,
                              hipStream_t stream) {
    const float* X  = (const float*)d_in[0];
    const float* W  = (const float*)d_in[1];
    const float* PE = (const float*)d_in[2];
    const int*   CI = (const int*)d_in[3];
    const int*   CM = (const int*)d_in[4];
    const int*   SL = (const int*)d_in[5];
    float* OUT = (float*)d_out;
    __half* PW  = (__half*)d_ws;                       // 96*512*2 = 96 KiB
    __half* PEh = (__half*)d_ws + (size_t)VV * DIN;    // +96*128*2 = 24 KiB

    hipLaunchKernelGGL(pw_kernel, dim3(VV, 4), dim3(128), 0, stream, W, PE, PW, PEh);

    const int rows = BB * LL;            // 65536
    hipLaunchKernelGGL(attn_kernel, dim3(rows / 128), dim3(1024), 0, stream,
                       X, PW, PEh, CI, CM, SL, OUT);
}